// Round 7
// baseline (1435.745 us; speedup 1.0000x reference)
//
#include <hip/hip_runtime.h>

#define NN 50000
#define NE 1600000
#define NG 64
#define HD 64
#define BN_EPS 1e-5f
#define NTILES ((NN + 31) / 32)

typedef unsigned short ushort_t;
typedef unsigned int uint_t;
typedef __attribute__((ext_vector_type(8))) short bf16x8;
typedef __attribute__((ext_vector_type(4))) float f32x4;

__device__ __forceinline__ float b2f(ushort_t u) {
  union { uint_t i; float f; } v; v.i = ((uint_t)u) << 16; return v.f;
}
__device__ __forceinline__ ushort_t f2b(float f) {
  union { float f; uint_t i; } v; v.f = f;
  uint_t x = v.i;
  return (ushort_t)((x + 0x7fffu + ((x >> 16) & 1u)) >> 16);
}
// pack f32 into (bf16_hi | bf16_lo<<16); hi+lo reconstructs f to ~2^-17 rel
__device__ __forceinline__ uint_t packsplit(float f) {
  ushort_t hi = f2b(f);
  float r = f - b2f(hi);
  ushort_t lo = f2b(r);
  return (uint_t)hi | ((uint_t)lo << 16);
}
__device__ __forceinline__ float LDF(const void* p, int i, int isb) {
  return isb ? b2f(((const ushort_t*)p)[i]) : ((const float*)p)[i];
}
__device__ __forceinline__ int LDI(const void* p, int i, int is64) {
  return is64 ? ((const int*)p)[2 * i] : ((const int*)p)[i];
}
__device__ __forceinline__ int clampi(int v, int hi) {
  return (v < 0) ? 0 : (v >= hi ? hi - 1 : v);
}

// Sniff dtypes from bit patterns (bf16 exp-byte clustering; int64 high words zero).
__global__ void detect_k(const uint_t* __restrict__ xw, const uint_t* __restrict__ ew,
                         int* __restrict__ flags) {
  int t = threadIdx.x;  // 64 threads
  uint_t w = xw[t];
  uint_t b = (w >> 8) & 0x7fu;
  unsigned long long m1 = __ballot(b >= 0x3au && b <= 0x42u);
  unsigned long long m2 = __ballot(ew[2 * t + 1] == 0u);
  if (t == 0) {
    flags[0] = (__popcll(m1) >= 32) ? 1 : 0;
    flags[1] = (__popcll(m2) >= 56) ? 1 : 0;
  }
}

__global__ void __launch_bounds__(256) node_embed(
    const void* __restrict__ x, const void* __restrict__ W,
    const void* __restrict__ b, float* __restrict__ h, const int* __restrict__ flags) {
  __shared__ float xs[64 * 32];
  int isb = flags[0];
  int t = threadIdx.x;
  int base = blockIdx.x * 64;
  int nodes = NN - base; if (nodes > 64) nodes = 64;
  int idx = t * 8;
  if (idx < nodes * 32) {
    if (isb) {
      const uint4* p = (const uint4*)((const ushort_t*)x + base * 32);
      uint4 u = p[t];
      ushort_t* pu = (ushort_t*)&u;
      #pragma unroll
      for (int q = 0; q < 8; q++) xs[idx + q] = b2f(pu[q]);
    } else {
      const float4* p = (const float4*)((const float*)x + base * 32);
      float4 a = p[2 * t], d = p[2 * t + 1];
      xs[idx + 0] = a.x; xs[idx + 1] = a.y; xs[idx + 2] = a.z; xs[idx + 3] = a.w;
      xs[idx + 4] = d.x; xs[idx + 5] = d.y; xs[idx + 6] = d.z; xs[idx + 7] = d.w;
    }
  }
  int c = t & 63, s0 = t >> 6;
  float w[32];
  #pragma unroll
  for (int k = 0; k < 32; k++) w[k] = LDF(W, k * 64 + c, isb);
  float bc = LDF(b, c, isb);
  __syncthreads();
  #pragma unroll 4
  for (int i = 0; i < 16; i++) {
    int slot = s0 * 16 + i;
    int node = base + slot;
    if (node < NN) {
      float acc = bc;
      #pragma unroll
      for (int k = 0; k < 32; k++) acc += xs[slot * 32 + k] * w[k];
      h[node * 64 + c] = acc;
    }
  }
}

// ---------- counting sort of edges by dst (once per call) ----------
__global__ void __launch_bounds__(256) hist_k(
    const void* __restrict__ eidx, int* __restrict__ hist, const int* __restrict__ flags) {
  int is64 = flags[1];
  int e = blockIdx.x * 256 + threadIdx.x;
  if (e >= NE) return;
  int d = clampi(LDI(eidx, NE + e, is64), NN);
  atomicAdd(&hist[d], 1);
}

__global__ void __launch_bounds__(1024) scan_k(
    const int* __restrict__ hist, int* __restrict__ offs) {
  __shared__ int buf[1024];
  int t = threadIdx.x;
  int beg = t * 49, end = beg + 49; if (end > NN) end = NN; if (beg > NN) beg = NN;
  int s = 0;
  for (int i = beg; i < end; i++) s += hist[i];
  buf[t] = s;
  __syncthreads();
  for (int d = 1; d < 1024; d <<= 1) {
    int x = (t >= d) ? buf[t - d] : 0;
    __syncthreads();
    buf[t] += x;
    __syncthreads();
  }
  int run = buf[t] - s;
  for (int i = beg; i < end; i++) { int hv = hist[i]; offs[i] = run; run += hv; }
  if (t == 1023) offs[NN] = run;
}

__global__ void __launch_bounds__(256) scatter_k(
    const void* __restrict__ eidx, int* __restrict__ cursor,
    int* __restrict__ perm, int* __restrict__ psrc, int* __restrict__ pdst,
    const int* __restrict__ flags) {
  int is64 = flags[1];
  int e = blockIdx.x * 256 + threadIdx.x;
  if (e >= NE) return;
  int d = clampi(LDI(eidx, NE + e, is64), NN);
  int s = clampi(LDI(eidx, e, is64), NN);
  int pos = atomicAdd(&cursor[d], 1);
  perm[pos] = e;
  psrc[pos] = s;
  pdst[pos] = d;
}

// dst-sorted edge pass: register run-accumulation, one atomic flush per dst-run.
__global__ void __launch_bounds__(256) edge_sorted(
    const void* __restrict__ eattr, const int* __restrict__ perm,
    const int* __restrict__ psrc, const int* __restrict__ pdst,
    const void* __restrict__ eW, const void* __restrict__ eb,
    const float* __restrict__ h, float* __restrict__ agg, const int* __restrict__ flags) {
  __shared__ float ea[64 * 16];
  __shared__ int ss[64], sd[64];
  int isb = flags[0];
  int t = threadIdx.x;
  int base = blockIdx.x * 64;  // 25000 blocks exact
  if (t < 64) ss[t] = psrc[base + t];
  else if (t < 128) sd[t - 64] = pdst[base + t - 64];
  {
    int slot = t >> 2, q = t & 3;
    int pe = perm[base + slot];
    if (isb) {
      const uint2* p = (const uint2*)((const ushort_t*)eattr + (size_t)pe * 16 + q * 4);
      uint2 u = *p;
      ea[slot * 16 + q * 4 + 0] = b2f((ushort_t)(u.x & 0xffffu));
      ea[slot * 16 + q * 4 + 1] = b2f((ushort_t)(u.x >> 16));
      ea[slot * 16 + q * 4 + 2] = b2f((ushort_t)(u.y & 0xffffu));
      ea[slot * 16 + q * 4 + 3] = b2f((ushort_t)(u.y >> 16));
    } else {
      const float4* p = (const float4*)((const float*)eattr + (size_t)pe * 16 + q * 4);
      float4 v = *p;
      ea[slot * 16 + q * 4 + 0] = v.x;
      ea[slot * 16 + q * 4 + 1] = v.y;
      ea[slot * 16 + q * 4 + 2] = v.z;
      ea[slot * 16 + q * 4 + 3] = v.w;
    }
  }
  int c = t & 63, s0 = t >> 6;
  float w[16];
  #pragma unroll
  for (int k = 0; k < 16; k++) w[k] = LDF(eW, k * 64 + c, isb);
  float bc = LDF(eb, c, isb);
  __syncthreads();
  float acc = 0.f;
  int cur = -1;
  for (int i = 0; i < 16; i++) {
    int slot = s0 * 16 + i;
    int sn = ss[slot], dn = sd[slot];
    float e = bc;
    #pragma unroll
    for (int k = 0; k < 16; k++) e += ea[slot * 16 + k] * w[k];
    float m = h[sn * 64 + c] + e;
    m = m > 0.f ? m : 0.f;
    if (dn != cur) {  // wave-uniform
      if (cur >= 0) atomicAdd(&agg[cur * 64 + c], acc);
      cur = dn; acc = 0.f;
    }
    acc += m;
  }
  if (cur >= 0) atomicAdd(&agg[cur * 64 + c], acc);
}

// ---------------- MFMA MLP + BN stats (R5-verified version) ----------------
// z2 = relu((h+agg)@W1+b1)@W2+b2 via v_mfma_f32_16x16x32_bf16 with hi/lo
// split of activations. Safe if z2out aliases agg (tile staged to LDS behind
// a barrier before overwrite). ONE 32-row tile per block at grid=NTILES.
__global__ void __launch_bounds__(256) mlp_mfma(
    const float* __restrict__ h, const float* agg,
    const void* __restrict__ W1s, const void* __restrict__ b1s,
    const void* __restrict__ W2s, const void* __restrict__ b2s,
    float* z2out, float* __restrict__ bnsum, const int* __restrict__ flags, int layer) {
  __shared__ uint_t zs[32 * 65];    // packed hi|lo of z, stride 65
  __shared__ uint_t a1s[32 * 129];  // packed hi|lo of a1, stride 129
  int isb = flags[0];
  int t = threadIdx.x;
  int w = t >> 6, lane = t & 63, q = lane >> 4, m = lane & 15;
  int mt = w & 1;             // m-tile for both phases
  int ng1 = (w >> 1) * 4;     // phase1: 4 n-tiles (of 8)
  int ng2 = (w >> 1) * 2;     // phase2: 2 n-tiles (of 4)
  int w1off = layer * 64 * 128, b1off = layer * 128;
  int w2off = layer * 128 * 64, b2off = layer * 64;

  // weight fragments in registers (hi part; exact when isb=1)
  bf16x8 w1h[4][2], w2h[2][4];
  #pragma unroll
  for (int i = 0; i < 4; i++)
    #pragma unroll
    for (int kc = 0; kc < 2; kc++) {
      bf16x8 f;
      #pragma unroll
      for (int j = 0; j < 8; j++) {
        int idx = w1off + (kc * 32 + q * 8 + j) * 128 + (ng1 + i) * 16 + m;
        f[j] = (short)(isb ? ((const ushort_t*)W1s)[idx] : f2b(((const float*)W1s)[idx]));
      }
      w1h[i][kc] = f;
    }
  #pragma unroll
  for (int i = 0; i < 2; i++)
    #pragma unroll
    for (int kc = 0; kc < 4; kc++) {
      bf16x8 f;
      #pragma unroll
      for (int j = 0; j < 8; j++) {
        int idx = w2off + (kc * 32 + q * 8 + j) * 64 + (ng2 + i) * 16 + m;
        f[j] = (short)(isb ? ((const ushort_t*)W2s)[idx] : f2b(((const float*)W2s)[idx]));
      }
      w2h[i][kc] = f;
    }
  float b1v[4], b2v[2];
  #pragma unroll
  for (int i = 0; i < 4; i++) b1v[i] = LDF(b1s, b1off + (ng1 + i) * 16 + m, isb);
  #pragma unroll
  for (int i = 0; i < 2; i++) b2v[i] = LDF(b2s, b2off + (ng2 + i) * 16 + m, isb);

  int srow = t >> 3, scol = (t & 7) * 8;  // staging role: 8 elems of one row
  float ps[2] = {0.f, 0.f}, pq[2] = {0.f, 0.f};

  for (int tile = blockIdx.x; tile < NTILES; tile += gridDim.x) {
    int base = tile * 32;
    __syncthreads();
    {
      int gr = base + srow;
      if (gr < NN) {
        const float4* hp = (const float4*)(h + (size_t)gr * 64 + scol);
        const float4* ap = (const float4*)(agg + (size_t)gr * 64 + scol);
        float4 h0 = hp[0], h1 = hp[1], a0 = ap[0], a1 = ap[1];
        zs[srow * 65 + scol + 0] = packsplit(h0.x + a0.x);
        zs[srow * 65 + scol + 1] = packsplit(h0.y + a0.y);
        zs[srow * 65 + scol + 2] = packsplit(h0.z + a0.z);
        zs[srow * 65 + scol + 3] = packsplit(h0.w + a0.w);
        zs[srow * 65 + scol + 4] = packsplit(h1.x + a1.x);
        zs[srow * 65 + scol + 5] = packsplit(h1.y + a1.y);
        zs[srow * 65 + scol + 6] = packsplit(h1.z + a1.z);
        zs[srow * 65 + scol + 7] = packsplit(h1.w + a1.w);
      } else {
        #pragma unroll
        for (int jj = 0; jj < 8; jj++) zs[srow * 65 + scol + jj] = 0;
      }
    }
    __syncthreads();
    // phase 1: A(16x64) @ W1(64x128) for this wave's m-tile & 4 n-tiles
    f32x4 acc1[4];
    #pragma unroll
    for (int i = 0; i < 4; i++) acc1[i] = (f32x4){0.f, 0.f, 0.f, 0.f};
    #pragma unroll
    for (int kc = 0; kc < 2; kc++) {
      int ab = (mt * 16 + m) * 65 + kc * 32 + q * 8;
      bf16x8 ahi, alo;
      #pragma unroll
      for (int j = 0; j < 8; j++) {
        uint_t u = zs[ab + j];
        ahi[j] = (short)(u & 0xffffu);
        alo[j] = (short)(u >> 16);
      }
      #pragma unroll
      for (int i = 0; i < 4; i++) {
        acc1[i] = __builtin_amdgcn_mfma_f32_16x16x32_bf16(ahi, w1h[i][kc], acc1[i], 0, 0, 0);
        acc1[i] = __builtin_amdgcn_mfma_f32_16x16x32_bf16(alo, w1h[i][kc], acc1[i], 0, 0, 0);
        if (!isb) {  // f32 weights: add Ahi * Blo correction
          bf16x8 blo;
          #pragma unroll
          for (int j = 0; j < 8; j++) {
            int idx = w1off + (kc * 32 + q * 8 + j) * 128 + (ng1 + i) * 16 + m;
            float wf = ((const float*)W1s)[idx];
            blo[j] = (short)f2b(wf - b2f(f2b(wf)));
          }
          acc1[i] = __builtin_amdgcn_mfma_f32_16x16x32_bf16(ahi, blo, acc1[i], 0, 0, 0);
        }
      }
    }
    // bias + relu + split-pack into a1s
    #pragma unroll
    for (int i = 0; i < 4; i++) {
      #pragma unroll
      for (int r = 0; r < 4; r++) {
        float v = acc1[i][r] + b1v[i];
        v = v > 0.f ? v : 0.f;
        a1s[(mt * 16 + q * 4 + r) * 129 + (ng1 + i) * 16 + m] = packsplit(v);
      }
    }
    __syncthreads();
    // phase 2: A1(16x128) @ W2(128x64) for this wave's m-tile & 2 n-tiles
    f32x4 acc2[2];
    #pragma unroll
    for (int i = 0; i < 2; i++) acc2[i] = (f32x4){0.f, 0.f, 0.f, 0.f};
    #pragma unroll
    for (int kc = 0; kc < 4; kc++) {
      int ab = (mt * 16 + m) * 129 + kc * 32 + q * 8;
      bf16x8 ahi, alo;
      #pragma unroll
      for (int j = 0; j < 8; j++) {
        uint_t u = a1s[ab + j];
        ahi[j] = (short)(u & 0xffffu);
        alo[j] = (short)(u >> 16);
      }
      #pragma unroll
      for (int i = 0; i < 2; i++) {
        acc2[i] = __builtin_amdgcn_mfma_f32_16x16x32_bf16(ahi, w2h[i][kc], acc2[i], 0, 0, 0);
        acc2[i] = __builtin_amdgcn_mfma_f32_16x16x32_bf16(alo, w2h[i][kc], acc2[i], 0, 0, 0);
        if (!isb) {
          bf16x8 blo;
          #pragma unroll
          for (int j = 0; j < 8; j++) {
            int idx = w2off + (kc * 32 + q * 8 + j) * 64 + (ng2 + i) * 16 + m;
            float wf = ((const float*)W2s)[idx];
            blo[j] = (short)f2b(wf - b2f(f2b(wf)));
          }
          acc2[i] = __builtin_amdgcn_mfma_f32_16x16x32_bf16(ahi, blo, acc2[i], 0, 0, 0);
        }
      }
    }
    // write z2 + accumulate BN partials (row-guarded)
    #pragma unroll
    for (int i = 0; i < 2; i++) {
      int col = (ng2 + i) * 16 + m;
      #pragma unroll
      for (int r = 0; r < 4; r++) {
        int gr = base + mt * 16 + q * 4 + r;
        if (gr < NN) {
          float v = acc2[i][r] + b2v[i];
          z2out[(size_t)gr * 64 + col] = v;
          ps[i] += v; pq[i] += v * v;
        }
      }
    }
  }
  // block-level BN reduction, then one global atomic per channel pair
  __syncthreads();
  float* red = (float*)zs;
  if (t < 128) red[t] = 0.f;
  __syncthreads();
  #pragma unroll
  for (int i = 0; i < 2; i++) {
    int col = (ng2 + i) * 16 + m;
    atomicAdd(&red[col], ps[i]);
    atomicAdd(&red[64 + col], pq[i]);
  }
  __syncthreads();
  if (t < 128) atomicAdd(&bnsum[t], red[t]);
}

__global__ void bn_fin(const float* __restrict__ bnsum, const void* __restrict__ gammas,
                       const void* __restrict__ betas, float* __restrict__ scsh,
                       const int* __restrict__ flags, int layer) {
  int c = threadIdx.x;  // 64
  int isb = flags[0];
  float inv_n = 1.0f / (float)NN;
  float mu = bnsum[c] * inv_n;
  float var = bnsum[64 + c] * inv_n - mu * mu;
  var = var > 0.f ? var : 0.f;
  float sc = LDF(gammas, layer * 64 + c, isb) * rsqrtf(var + BN_EPS);
  scsh[c] = sc;
  scsh[64 + c] = LDF(betas, layer * 64 + c, isb) - mu * sc;
}

__global__ void __launch_bounds__(256) bn_apply(
    const float* __restrict__ z2, const float* __restrict__ scsh, float* __restrict__ h) {
  int t = blockIdx.x * 256 + threadIdx.x;
  if (t < NN * 16) {
    float4 z = ((const float4*)z2)[t];
    int c4 = t & 15;
    float4 sc = ((const float4*)scsh)[c4];
    float4 sh = ((const float4*)(scsh + 64))[c4];
    float4 r;
    r.x = fmaxf(z.x * sc.x + sh.x, 0.f);
    r.y = fmaxf(z.y * sc.y + sh.y, 0.f);
    r.z = fmaxf(z.z * sc.z + sh.z, 0.f);
    r.w = fmaxf(z.w * sc.w + sh.w, 0.f);
    ((float4*)h)[t] = r;
  }
}

// batch is sorted: bounds[g] = first i with batch[i] >= g; bounds[NG] = NN.
__global__ void __launch_bounds__(256) find_bounds(
    const void* __restrict__ batch, int* __restrict__ bounds, const int* __restrict__ flags) {
  int is64 = flags[1];
  int i = blockIdx.x * 256 + threadIdx.x;
  if (i >= NN) return;
  int cur = clampi(LDI(batch, i, is64), NG);
  if (i == 0) {
    for (int g = 0; g <= cur; g++) bounds[g] = 0;
  } else {
    int prev = clampi(LDI(batch, i - 1, is64), NG);
    for (int g = prev + 1; g <= cur; g++) bounds[g] = i;
  }
  if (i == NN - 1) {
    for (int g = cur + 1; g <= NG; g++) bounds[g] = NN;
  }
}

__global__ void __launch_bounds__(256) pool_final(
    const float* __restrict__ h, const int* __restrict__ bounds,
    const void* __restrict__ linW, const void* __restrict__ linB,
    float* __restrict__ out, const int* __restrict__ flags) {
  __shared__ float red[4][64];
  int isb = flags[0];
  int g = blockIdx.x;
  int t = threadIdx.x, c = t & 63, w = t >> 6;
  int s = bounds[g], e = bounds[g + 1];
  float acc = 0.f;
  for (int i = s + w; i < e; i += 4) acc += h[i * 64 + c];
  red[w][c] = acc;
  __syncthreads();
  if (t < 64) {
    float v = red[0][c] + red[1][c] + red[2][c] + red[3][c];
    float cnt = (float)(e - s); if (cnt < 1.f) cnt = 1.f;
    v = (v / cnt) * LDF(linW, c, isb);
    #pragma unroll
    for (int m = 32; m >= 1; m >>= 1) v += __shfl_xor(v, m, 64);
    if (c == 0) out[g] = v + LDF(linB, 0, isb);
  }
}

extern "C" void kernel_launch(void* const* d_in, const int* in_sizes, int n_in,
                              void* d_out, int out_size, void* d_ws, size_t ws_size,
                              hipStream_t stream) {
  const void* x     = d_in[0];
  const void* eattr = d_in[1];
  const void* eidx  = d_in[2];
  const void* batch = d_in[3];
  const void* nodeW = d_in[4];
  const void* nodeB = d_in[5];
  const void* edgeW = d_in[6];
  const void* edgeB = d_in[7];
  const void* W1s   = d_in[8];
  const void* b1s   = d_in[9];
  const void* W2s   = d_in[10];
  const void* b2s   = d_in[11];
  const void* gam   = d_in[12];
  const void* bet   = d_in[13];
  const void* linW  = d_in[14];
  const void* linB  = d_in[15];
  float* out = (float*)d_out;

  int*   flags  = (int*)d_ws;
  float* h      = (float*)d_ws + 16;
  float* agg    = h + (size_t)NN * HD;
  float* bnsum  = agg + (size_t)NN * HD;   // 128
  float* scsh   = bnsum + 128;             // 128
  int*   bounds = (int*)(scsh + 128);      // 80 slots
  int*   offs   = bounds + 80;             // NN+1
  int*   cursor = offs + (NN + 1);         // NN+1
  int*   perm   = cursor + (NN + 1);       // NE
  int*   psrc   = perm + NE;               // NE
  int*   pdst   = psrc + NE;               // NE
  float* z2sep  = (float*)(pdst + NE);     // NN*HD (optional)

  size_t base_words  = 16ull + 2ull * NN * HD + 128 + 128 + 80;
  size_t sort_words  = base_words + 2ull * (NN + 1) + 3ull * NE;
  size_t needed_sort = sort_words * 4ull;
  if (ws_size < needed_sort) return;  // avoid faulting if scratch too small
  // un-alias z2 from agg when scratch allows (kernel is alias-safe either way)
  float* z2 = (ws_size >= (sort_words + (size_t)NN * HD) * 4ull) ? z2sep : agg;

  detect_k<<<1, 64, 0, stream>>>((const uint_t*)x, (const uint_t*)eidx, flags);
  node_embed<<<(NN + 63) / 64, 256, 0, stream>>>(x, nodeW, nodeB, h, flags);

  hipMemsetAsync(offs, 0, (NN + 1) * sizeof(int), stream);
  hist_k<<<NE / 256, 256, 0, stream>>>(eidx, offs, flags);
  scan_k<<<1, 1024, 0, stream>>>(offs, cursor);
  scatter_k<<<NE / 256, 256, 0, stream>>>(eidx, cursor, perm, psrc, pdst, flags);

  for (int l = 0; l < 3; l++) {
    hipMemsetAsync(agg, 0, (size_t)NN * HD * sizeof(float), stream);
    edge_sorted<<<NE / 64, 256, 0, stream>>>(eattr, perm, psrc, pdst, edgeW, edgeB, h, agg, flags);
    hipMemsetAsync(bnsum, 0, 128 * sizeof(float), stream);
    mlp_mfma<<<NTILES, 256, 0, stream>>>(h, agg, W1s, b1s, W2s, b2s, z2, bnsum, flags, l);
    bn_fin<<<1, 64, 0, stream>>>(bnsum, gam, bet, scsh, flags, l);
    bn_apply<<<3125, 256, 0, stream>>>(z2, scsh, h);
  }
  find_bounds<<<(NN + 255) / 256, 256, 0, stream>>>(batch, bounds, flags);
  pool_final<<<NG, 256, 0, stream>>>(h, bounds, linW, linB, out, flags);
}

// Round 8
// 957.995 us; speedup vs baseline: 1.4987x; 1.4987x over previous
//
#include <hip/hip_runtime.h>

#define NN 50000
#define NE 1600000
#define NG 64
#define HD 64
#define BN_EPS 1e-5f
#define NTILES ((NN + 31) / 32)

typedef unsigned short ushort_t;
typedef unsigned int uint_t;
typedef __attribute__((ext_vector_type(8))) short bf16x8;
typedef __attribute__((ext_vector_type(4))) float f32x4;

__device__ __forceinline__ float b2f(ushort_t u) {
  union { uint_t i; float f; } v; v.i = ((uint_t)u) << 16; return v.f;
}
__device__ __forceinline__ ushort_t f2b(float f) {
  union { float f; uint_t i; } v; v.f = f;
  uint_t x = v.i;
  return (ushort_t)((x + 0x7fffu + ((x >> 16) & 1u)) >> 16);
}
// pack f32 into (bf16_hi | bf16_lo<<16); hi+lo reconstructs f to ~2^-17 rel
__device__ __forceinline__ uint_t packsplit(float f) {
  ushort_t hi = f2b(f);
  float r = f - b2f(hi);
  ushort_t lo = f2b(r);
  return (uint_t)hi | ((uint_t)lo << 16);
}
__device__ __forceinline__ float LDF(const void* p, int i, int isb) {
  return isb ? b2f(((const ushort_t*)p)[i]) : ((const float*)p)[i];
}
__device__ __forceinline__ int LDI(const void* p, int i, int is64) {
  return is64 ? ((const int*)p)[2 * i] : ((const int*)p)[i];
}
__device__ __forceinline__ int clampi(int v, int hi) {
  return (v < 0) ? 0 : (v >= hi ? hi - 1 : v);
}

// Sniff dtypes from bit patterns (bf16 exp-byte clustering; int64 high words zero).
__global__ void detect_k(const uint_t* __restrict__ xw, const uint_t* __restrict__ ew,
                         int* __restrict__ flags) {
  int t = threadIdx.x;  // 64 threads
  uint_t w = xw[t];
  uint_t b = (w >> 8) & 0x7fu;
  unsigned long long m1 = __ballot(b >= 0x3au && b <= 0x42u);
  unsigned long long m2 = __ballot(ew[2 * t + 1] == 0u);
  if (t == 0) {
    flags[0] = (__popcll(m1) >= 32) ? 1 : 0;
    flags[1] = (__popcll(m2) >= 56) ? 1 : 0;
  }
}

__global__ void __launch_bounds__(256) node_embed(
    const void* __restrict__ x, const void* __restrict__ W,
    const void* __restrict__ b, float* __restrict__ h, const int* __restrict__ flags) {
  __shared__ float xs[64 * 32];
  int isb = flags[0];
  int t = threadIdx.x;
  int base = blockIdx.x * 64;
  int nodes = NN - base; if (nodes > 64) nodes = 64;
  int idx = t * 8;
  if (idx < nodes * 32) {
    if (isb) {
      const uint4* p = (const uint4*)((const ushort_t*)x + base * 32);
      uint4 u = p[t];
      ushort_t* pu = (ushort_t*)&u;
      #pragma unroll
      for (int q = 0; q < 8; q++) xs[idx + q] = b2f(pu[q]);
    } else {
      const float4* p = (const float4*)((const float*)x + base * 32);
      float4 a = p[2 * t], d = p[2 * t + 1];
      xs[idx + 0] = a.x; xs[idx + 1] = a.y; xs[idx + 2] = a.z; xs[idx + 3] = a.w;
      xs[idx + 4] = d.x; xs[idx + 5] = d.y; xs[idx + 6] = d.z; xs[idx + 7] = d.w;
    }
  }
  int c = t & 63, s0 = t >> 6;
  float w[32];
  #pragma unroll
  for (int k = 0; k < 32; k++) w[k] = LDF(W, k * 64 + c, isb);
  float bc = LDF(b, c, isb);
  __syncthreads();
  #pragma unroll 4
  for (int i = 0; i < 16; i++) {
    int slot = s0 * 16 + i;
    int node = base + slot;
    if (node < NN) {
      float acc = bc;
      #pragma unroll
      for (int k = 0; k < 32; k++) acc += xs[slot * 32 + k] * w[k];
      h[node * 64 + c] = acc;
    }
  }
}

// ---------- counting sort of edges by dst (once per call) ----------
__global__ void __launch_bounds__(256) hist_k(
    const void* __restrict__ eidx, int* __restrict__ hist, const int* __restrict__ flags) {
  int is64 = flags[1];
  int e = blockIdx.x * 256 + threadIdx.x;
  if (e >= NE) return;
  int d = clampi(LDI(eidx, NE + e, is64), NN);
  atomicAdd(&hist[d], 1);
}

__global__ void __launch_bounds__(1024) scan_k(
    const int* __restrict__ hist, int* __restrict__ offs) {
  __shared__ int buf[1024];
  int t = threadIdx.x;
  int beg = t * 49, end = beg + 49; if (end > NN) end = NN; if (beg > NN) beg = NN;
  int s = 0;
  for (int i = beg; i < end; i++) s += hist[i];
  buf[t] = s;
  __syncthreads();
  for (int d = 1; d < 1024; d <<= 1) {
    int x = (t >= d) ? buf[t - d] : 0;
    __syncthreads();
    buf[t] += x;
    __syncthreads();
  }
  int run = buf[t] - s;
  for (int i = beg; i < end; i++) { int hv = hist[i]; offs[i] = run; run += hv; }
  if (t == 1023) offs[NN] = run;
}

__global__ void __launch_bounds__(256) scatter_k(
    const void* __restrict__ eidx, int* __restrict__ cursor,
    int* __restrict__ perm, int* __restrict__ psrc, int* __restrict__ pdst,
    const int* __restrict__ flags) {
  int is64 = flags[1];
  int e = blockIdx.x * 256 + threadIdx.x;
  if (e >= NE) return;
  int d = clampi(LDI(eidx, NE + e, is64), NN);
  int s = clampi(LDI(eidx, e, is64), NN);
  int pos = atomicAdd(&cursor[d], 1);
  perm[pos] = e;
  psrc[pos] = s;
  pdst[pos] = d;
}

// dst-sorted edge pass: register run-accumulation, one atomic flush per dst-run.
__global__ void __launch_bounds__(256) edge_sorted(
    const void* __restrict__ eattr, const int* __restrict__ perm,
    const int* __restrict__ psrc, const int* __restrict__ pdst,
    const void* __restrict__ eW, const void* __restrict__ eb,
    const float* __restrict__ h, float* __restrict__ agg, const int* __restrict__ flags) {
  __shared__ float ea[64 * 16];
  __shared__ int ss[64], sd[64];
  int isb = flags[0];
  int t = threadIdx.x;
  int base = blockIdx.x * 64;  // 25000 blocks exact
  if (t < 64) ss[t] = psrc[base + t];
  else if (t < 128) sd[t - 64] = pdst[base + t - 64];
  {
    int slot = t >> 2, q = t & 3;
    int pe = perm[base + slot];
    if (isb) {
      const uint2* p = (const uint2*)((const ushort_t*)eattr + (size_t)pe * 16 + q * 4);
      uint2 u = *p;
      ea[slot * 16 + q * 4 + 0] = b2f((ushort_t)(u.x & 0xffffu));
      ea[slot * 16 + q * 4 + 1] = b2f((ushort_t)(u.x >> 16));
      ea[slot * 16 + q * 4 + 2] = b2f((ushort_t)(u.y & 0xffffu));
      ea[slot * 16 + q * 4 + 3] = b2f((ushort_t)(u.y >> 16));
    } else {
      const float4* p = (const float4*)((const float*)eattr + (size_t)pe * 16 + q * 4);
      float4 v = *p;
      ea[slot * 16 + q * 4 + 0] = v.x;
      ea[slot * 16 + q * 4 + 1] = v.y;
      ea[slot * 16 + q * 4 + 2] = v.z;
      ea[slot * 16 + q * 4 + 3] = v.w;
    }
  }
  int c = t & 63, s0 = t >> 6;
  float w[16];
  #pragma unroll
  for (int k = 0; k < 16; k++) w[k] = LDF(eW, k * 64 + c, isb);
  float bc = LDF(eb, c, isb);
  __syncthreads();
  float acc = 0.f;
  int cur = -1;
  for (int i = 0; i < 16; i++) {
    int slot = s0 * 16 + i;
    int sn = ss[slot], dn = sd[slot];
    float e = bc;
    #pragma unroll
    for (int k = 0; k < 16; k++) e += ea[slot * 16 + k] * w[k];
    float m = h[sn * 64 + c] + e;
    m = m > 0.f ? m : 0.f;
    if (dn != cur) {  // wave-uniform
      if (cur >= 0) atomicAdd(&agg[cur * 64 + c], acc);
      cur = dn; acc = 0.f;
    }
    acc += m;
  }
  if (cur >= 0) atomicAdd(&agg[cur * 64 + c], acc);
}

// ---- weight prepack (once per call): fragment-ordered, coalesced-readable ----
// Layout per layer (uint4 units): w1hi[1024] | w1lo[1024] | w2hi[1024] | w2lo[1024]
// w1 frag addr: (half*8 + kc*4 + i)*64 + lane   element j = W1[kc*32+q*8+j][(half*4+i)*16+m]
// w2 frag addr: (half*8 + kc*2 + i)*64 + lane   element j = W2[kc*32+q*8+j][(half*2+i)*16+m]
// lo parts are exactly 0 when inputs are bf16 (wf - b2f(f2b(wf)) == 0).
__global__ void __launch_bounds__(256) prep_w(
    const void* __restrict__ W1s, const void* __restrict__ W2s,
    uint4* __restrict__ wpk, const int* __restrict__ flags) {
  int l = blockIdx.x, t = threadIdx.x, isb = flags[0];
  uint4* w1hi = wpk + (size_t)l * 4096;
  uint4* w1lo = w1hi + 1024;
  uint4* w2hi = w1hi + 2048;
  uint4* w2lo = w1hi + 3072;
  union U8 { ushort_t s[8]; uint4 u; };
  for (int o = t; o < 1024; o += 256) {
    int lane = o & 63, f = (o >> 6) & 7, hh = o >> 9;
    int q = lane >> 4, m = lane & 15;
    {
      int kc = f >> 2, i = f & 3;
      U8 hi, lo;
      #pragma unroll
      for (int j = 0; j < 8; j++) {
        int idx = l * 8192 + (kc * 32 + q * 8 + j) * 128 + (hh * 4 + i) * 16 + m;
        float wf = LDF(W1s, idx, isb);
        ushort_t hb = f2b(wf);
        hi.s[j] = hb;
        lo.s[j] = f2b(wf - b2f(hb));
      }
      w1hi[o] = hi.u;
      w1lo[o] = lo.u;
    }
    {
      int kc = f >> 1, i = f & 1;
      U8 hi, lo;
      #pragma unroll
      for (int j = 0; j < 8; j++) {
        int idx = l * 8192 + (kc * 32 + q * 8 + j) * 64 + (hh * 2 + i) * 16 + m;
        float wf = LDF(W2s, idx, isb);
        ushort_t hb = f2b(wf);
        hi.s[j] = hb;
        lo.s[j] = f2b(wf - b2f(hb));
      }
      w2hi[o] = hi.u;
      w2lo[o] = lo.u;
    }
  }
}

// ---------------- MFMA MLP + BN stats (R5-verified body, packed weights) ----
// z2 = relu((h+agg)@W1+b1)@W2+b2 via v_mfma_f32_16x16x32_bf16 with hi/lo
// split of activations. Alias-safe vs z2out==agg (tile staged to LDS behind a
// barrier before overwrite). Prologue: 16 coalesced uint4 loads per thread.
__global__ void __launch_bounds__(256) mlp_mfma(
    const float* __restrict__ h, const float* agg,
    const uint4* __restrict__ wpk, const void* __restrict__ b1s,
    const void* __restrict__ b2s,
    float* z2out, float* __restrict__ bnsum, const int* __restrict__ flags, int layer) {
  __shared__ uint_t zs[32 * 65];    // packed hi|lo of z, stride 65
  __shared__ uint_t a1s[32 * 129];  // packed hi|lo of a1, stride 129
  int isb = flags[0];
  int t = threadIdx.x;
  int w = t >> 6, lane = t & 63, q = lane >> 4, m = lane & 15;
  int mt = w & 1;             // m-tile for both phases
  int hh = w >> 1;            // n-half for both phases
  int ng1 = hh * 4;           // phase1: 4 n-tiles (of 8)
  int ng2 = hh * 2;           // phase2: 2 n-tiles (of 4)
  int b1off = layer * 128, b2off = layer * 64;
  const uint4* w1hi = wpk + (size_t)layer * 4096;
  const uint4* w1lo = w1hi + 1024;
  const uint4* w2hi = w1hi + 2048;
  const uint4* w2lo = w1hi + 3072;

  union FR { uint4 u; bf16x8 v; };
  FR w1f[4][2], w2f[2][4];
  #pragma unroll
  for (int kc = 0; kc < 2; kc++)
    #pragma unroll
    for (int i = 0; i < 4; i++)
      w1f[i][kc].u = w1hi[(hh * 8 + kc * 4 + i) * 64 + lane];
  #pragma unroll
  for (int kc = 0; kc < 4; kc++)
    #pragma unroll
    for (int i = 0; i < 2; i++)
      w2f[i][kc].u = w2hi[(hh * 8 + kc * 2 + i) * 64 + lane];

  float b1v[4], b2v[2];
  #pragma unroll
  for (int i = 0; i < 4; i++) b1v[i] = LDF(b1s, b1off + (ng1 + i) * 16 + m, isb);
  #pragma unroll
  for (int i = 0; i < 2; i++) b2v[i] = LDF(b2s, b2off + (ng2 + i) * 16 + m, isb);

  int srow = t >> 3, scol = (t & 7) * 8;  // staging role: 8 elems of one row
  float ps[2] = {0.f, 0.f}, pq[2] = {0.f, 0.f};

  for (int tile = blockIdx.x; tile < NTILES; tile += gridDim.x) {
    int base = tile * 32;
    __syncthreads();
    {
      int gr = base + srow;
      if (gr < NN) {
        const float4* hp = (const float4*)(h + (size_t)gr * 64 + scol);
        const float4* ap = (const float4*)(agg + (size_t)gr * 64 + scol);
        float4 h0 = hp[0], h1 = hp[1], a0 = ap[0], a1 = ap[1];
        zs[srow * 65 + scol + 0] = packsplit(h0.x + a0.x);
        zs[srow * 65 + scol + 1] = packsplit(h0.y + a0.y);
        zs[srow * 65 + scol + 2] = packsplit(h0.z + a0.z);
        zs[srow * 65 + scol + 3] = packsplit(h0.w + a0.w);
        zs[srow * 65 + scol + 4] = packsplit(h1.x + a1.x);
        zs[srow * 65 + scol + 5] = packsplit(h1.y + a1.y);
        zs[srow * 65 + scol + 6] = packsplit(h1.z + a1.z);
        zs[srow * 65 + scol + 7] = packsplit(h1.w + a1.w);
      } else {
        #pragma unroll
        for (int jj = 0; jj < 8; jj++) zs[srow * 65 + scol + jj] = 0;
      }
    }
    __syncthreads();
    // phase 1: A(16x64) @ W1(64x128) for this wave's m-tile & 4 n-tiles
    f32x4 acc1[4];
    #pragma unroll
    for (int i = 0; i < 4; i++) acc1[i] = (f32x4){0.f, 0.f, 0.f, 0.f};
    #pragma unroll
    for (int kc = 0; kc < 2; kc++) {
      int ab = (mt * 16 + m) * 65 + kc * 32 + q * 8;
      bf16x8 ahi, alo;
      #pragma unroll
      for (int j = 0; j < 8; j++) {
        uint_t u = zs[ab + j];
        ahi[j] = (short)(u & 0xffffu);
        alo[j] = (short)(u >> 16);
      }
      #pragma unroll
      for (int i = 0; i < 4; i++) {
        acc1[i] = __builtin_amdgcn_mfma_f32_16x16x32_bf16(ahi, w1f[i][kc].v, acc1[i], 0, 0, 0);
        acc1[i] = __builtin_amdgcn_mfma_f32_16x16x32_bf16(alo, w1f[i][kc].v, acc1[i], 0, 0, 0);
        if (!isb) {  // f32 weights: add Ahi * Blo correction (packed lo frag)
          FR bl;
          bl.u = w1lo[(hh * 8 + kc * 4 + i) * 64 + lane];
          acc1[i] = __builtin_amdgcn_mfma_f32_16x16x32_bf16(ahi, bl.v, acc1[i], 0, 0, 0);
        }
      }
    }
    // bias + relu + split-pack into a1s
    #pragma unroll
    for (int i = 0; i < 4; i++) {
      #pragma unroll
      for (int r = 0; r < 4; r++) {
        float v = acc1[i][r] + b1v[i];
        v = v > 0.f ? v : 0.f;
        a1s[(mt * 16 + q * 4 + r) * 129 + (ng1 + i) * 16 + m] = packsplit(v);
      }
    }
    __syncthreads();
    // phase 2: A1(16x128) @ W2(128x64) for this wave's m-tile & 2 n-tiles
    f32x4 acc2[2];
    #pragma unroll
    for (int i = 0; i < 2; i++) acc2[i] = (f32x4){0.f, 0.f, 0.f, 0.f};
    #pragma unroll
    for (int kc = 0; kc < 4; kc++) {
      int ab = (mt * 16 + m) * 129 + kc * 32 + q * 8;
      bf16x8 ahi, alo;
      #pragma unroll
      for (int j = 0; j < 8; j++) {
        uint_t u = a1s[ab + j];
        ahi[j] = (short)(u & 0xffffu);
        alo[j] = (short)(u >> 16);
      }
      #pragma unroll
      for (int i = 0; i < 2; i++) {
        acc2[i] = __builtin_amdgcn_mfma_f32_16x16x32_bf16(ahi, w2f[i][kc].v, acc2[i], 0, 0, 0);
        acc2[i] = __builtin_amdgcn_mfma_f32_16x16x32_bf16(alo, w2f[i][kc].v, acc2[i], 0, 0, 0);
        if (!isb) {
          FR bl;
          bl.u = w2lo[(hh * 8 + kc * 2 + i) * 64 + lane];
          acc2[i] = __builtin_amdgcn_mfma_f32_16x16x32_bf16(ahi, bl.v, acc2[i], 0, 0, 0);
        }
      }
    }
    // write z2 + accumulate BN partials (row-guarded)
    #pragma unroll
    for (int i = 0; i < 2; i++) {
      int col = (ng2 + i) * 16 + m;
      #pragma unroll
      for (int r = 0; r < 4; r++) {
        int gr = base + mt * 16 + q * 4 + r;
        if (gr < NN) {
          float v = acc2[i][r] + b2v[i];
          z2out[(size_t)gr * 64 + col] = v;
          ps[i] += v; pq[i] += v * v;
        }
      }
    }
  }
  // block-level BN reduction, then one global atomic per channel pair
  __syncthreads();
  float* red = (float*)zs;
  if (t < 128) red[t] = 0.f;
  __syncthreads();
  #pragma unroll
  for (int i = 0; i < 2; i++) {
    int col = (ng2 + i) * 16 + m;
    atomicAdd(&red[col], ps[i]);
    atomicAdd(&red[64 + col], pq[i]);
  }
  __syncthreads();
  if (t < 128) atomicAdd(&bnsum[t], red[t]);
}

__global__ void bn_fin(const float* __restrict__ bnsum, const void* __restrict__ gammas,
                       const void* __restrict__ betas, float* __restrict__ scsh,
                       const int* __restrict__ flags, int layer) {
  int c = threadIdx.x;  // 64
  int isb = flags[0];
  float inv_n = 1.0f / (float)NN;
  float mu = bnsum[c] * inv_n;
  float var = bnsum[64 + c] * inv_n - mu * mu;
  var = var > 0.f ? var : 0.f;
  float sc = LDF(gammas, layer * 64 + c, isb) * rsqrtf(var + BN_EPS);
  scsh[c] = sc;
  scsh[64 + c] = LDF(betas, layer * 64 + c, isb) - mu * sc;
}

__global__ void __launch_bounds__(256) bn_apply(
    const float* __restrict__ z2, const float* __restrict__ scsh, float* __restrict__ h) {
  int t = blockIdx.x * 256 + threadIdx.x;
  if (t < NN * 16) {
    float4 z = ((const float4*)z2)[t];
    int c4 = t & 15;
    float4 sc = ((const float4*)scsh)[c4];
    float4 sh = ((const float4*)(scsh + 64))[c4];
    float4 r;
    r.x = fmaxf(z.x * sc.x + sh.x, 0.f);
    r.y = fmaxf(z.y * sc.y + sh.y, 0.f);
    r.z = fmaxf(z.z * sc.z + sh.z, 0.f);
    r.w = fmaxf(z.w * sc.w + sh.w, 0.f);
    ((float4*)h)[t] = r;
  }
}

// batch is sorted: bounds[g] = first i with batch[i] >= g; bounds[NG] = NN.
__global__ void __launch_bounds__(256) find_bounds(
    const void* __restrict__ batch, int* __restrict__ bounds, const int* __restrict__ flags) {
  int is64 = flags[1];
  int i = blockIdx.x * 256 + threadIdx.x;
  if (i >= NN) return;
  int cur = clampi(LDI(batch, i, is64), NG);
  if (i == 0) {
    for (int g = 0; g <= cur; g++) bounds[g] = 0;
  } else {
    int prev = clampi(LDI(batch, i - 1, is64), NG);
    for (int g = prev + 1; g <= cur; g++) bounds[g] = i;
  }
  if (i == NN - 1) {
    for (int g = cur + 1; g <= NG; g++) bounds[g] = NN;
  }
}

__global__ void __launch_bounds__(256) pool_final(
    const float* __restrict__ h, const int* __restrict__ bounds,
    const void* __restrict__ linW, const void* __restrict__ linB,
    float* __restrict__ out, const int* __restrict__ flags) {
  __shared__ float red[4][64];
  int isb = flags[0];
  int g = blockIdx.x;
  int t = threadIdx.x, c = t & 63, w = t >> 6;
  int s = bounds[g], e = bounds[g + 1];
  float acc = 0.f;
  for (int i = s + w; i < e; i += 4) acc += h[i * 64 + c];
  red[w][c] = acc;
  __syncthreads();
  if (t < 64) {
    float v = red[0][c] + red[1][c] + red[2][c] + red[3][c];
    float cnt = (float)(e - s); if (cnt < 1.f) cnt = 1.f;
    v = (v / cnt) * LDF(linW, c, isb);
    #pragma unroll
    for (int m = 32; m >= 1; m >>= 1) v += __shfl_xor(v, m, 64);
    if (c == 0) out[g] = v + LDF(linB, 0, isb);
  }
}

extern "C" void kernel_launch(void* const* d_in, const int* in_sizes, int n_in,
                              void* d_out, int out_size, void* d_ws, size_t ws_size,
                              hipStream_t stream) {
  const void* x     = d_in[0];
  const void* eattr = d_in[1];
  const void* eidx  = d_in[2];
  const void* batch = d_in[3];
  const void* nodeW = d_in[4];
  const void* nodeB = d_in[5];
  const void* edgeW = d_in[6];
  const void* edgeB = d_in[7];
  const void* W1s   = d_in[8];
  const void* b1s   = d_in[9];
  const void* W2s   = d_in[10];
  const void* b2s   = d_in[11];
  const void* gam   = d_in[12];
  const void* bet   = d_in[13];
  const void* linW  = d_in[14];
  const void* linB  = d_in[15];
  float* out = (float*)d_out;

  int*   flags  = (int*)d_ws;
  float* h      = (float*)d_ws + 16;
  float* agg    = h + (size_t)NN * HD;
  float* bnsum  = agg + (size_t)NN * HD;   // 128
  float* scsh   = bnsum + 128;             // 128
  int*   bounds = (int*)(scsh + 128);      // 80 slots
  int*   offs   = bounds + 80;             // NN+1
  int*   cursor = offs + (NN + 1);         // NN+1
  int*   perm   = cursor + (NN + 1);       // NE
  int*   psrc   = perm + NE;               // NE
  int*   pdst   = psrc + NE;               // NE

  size_t base_words = 16ull + 2ull * NN * HD + 128 + 128 + 80;
  size_t sort_words = base_words + 2ull * (NN + 1) + 3ull * NE;
  size_t wpk_words_start = (sort_words + 3ull) & ~3ull;  // 16B-align for uint4
  size_t wpk_words = 3ull * 4096 * 4;                    // 3 layers x 4096 uint4
  size_t needed = (wpk_words_start + wpk_words) * 4ull;
  if (ws_size < needed) return;  // avoid faulting if scratch too small
  uint4* wpk = (uint4*)((float*)d_ws + wpk_words_start);
  // un-alias z2 from agg when scratch allows (kernel is alias-safe either way)
  float* z2sep = (float*)d_ws + wpk_words_start + wpk_words;
  float* z2 = (ws_size >= (wpk_words_start + wpk_words + (size_t)NN * HD) * 4ull)
                  ? z2sep : agg;

  detect_k<<<1, 64, 0, stream>>>((const uint_t*)x, (const uint_t*)eidx, flags);
  prep_w<<<3, 256, 0, stream>>>(W1s, W2s, wpk, flags);
  node_embed<<<(NN + 63) / 64, 256, 0, stream>>>(x, nodeW, nodeB, h, flags);

  hipMemsetAsync(offs, 0, (NN + 1) * sizeof(int), stream);
  hist_k<<<NE / 256, 256, 0, stream>>>(eidx, offs, flags);
  scan_k<<<1, 1024, 0, stream>>>(offs, cursor);
  scatter_k<<<NE / 256, 256, 0, stream>>>(eidx, cursor, perm, psrc, pdst, flags);

  for (int l = 0; l < 3; l++) {
    hipMemsetAsync(agg, 0, (size_t)NN * HD * sizeof(float), stream);
    edge_sorted<<<NE / 64, 256, 0, stream>>>(eattr, perm, psrc, pdst, edgeW, edgeB, h, agg, flags);
    hipMemsetAsync(bnsum, 0, 128 * sizeof(float), stream);
    mlp_mfma<<<784, 256, 0, stream>>>(h, agg, wpk, b1s, b2s, z2, bnsum, flags, l);
    bn_fin<<<1, 64, 0, stream>>>(bnsum, gam, bet, scsh, flags, l);
    bn_apply<<<3125, 256, 0, stream>>>(z2, scsh, h);
  }
  find_bounds<<<(NN + 255) / 256, 256, 0, stream>>>(batch, bounds, flags);
  pool_final<<<NG, 256, 0, stream>>>(h, bounds, linW, linB, out, flags);
}